// Round 3
// baseline (10312.135 us; speedup 1.0000x reference)
//
#include <hip/hip_runtime.h>

typedef unsigned short u16;

__device__ __forceinline__ float bf2f(u16 u){
  union{unsigned int i; float f;} v; v.i=((unsigned int)u)<<16; return v.f;
}
__device__ __forceinline__ u16 f2bf(float x){
  union{float f; unsigned int i;} v; v.f=x;
  unsigned int b=v.i;
  return (u16)((b + 0x7fffu + ((b>>16)&1u))>>16);
}
// mode: 0 = device arrays are bf16 (u16), 1 = device arrays are f32
__device__ __forceinline__ float ldf(const void* p, size_t i, int m){
  return m ? ((const float*)p)[i] : bf2f(((const u16*)p)[i]);
}

#define HEADS 4
#define HHID 256   // HEADS*HID

// ---- fill d_out with a u16 pattern (pairs [lo,hi] => f32 bits hi<<16|lo) ----
__global__ void TopoAggregator_33217277067466_kernel(u16* __restrict__ out, int n, u16 lo, u16 hi){
  for(int i = blockIdx.x*blockDim.x + threadIdx.x; i < n; i += gridDim.x*blockDim.x)
    out[i] = (i&1) ? hi : lo;
}

// ---- input dtype forensics ----
__global__ void k_detect(const void* __restrict__ nodes, int* __restrict__ diag){
  if(threadIdx.x!=0 || blockIdx.x!=0) return;
  const u16*   pu = (const u16*)nodes;
  const float* pf = (const float*)nodes;
  unsigned long long s = 0;
  for(int i=0;i<1000;i++) s += pu[i];
  int zero = (s==0ull) ? 1 : 0;
  int sb=0, sf=0;
  for(int r=0;r<8;r++){
    float lims[4]={288.f,16.f,2.f,2.f};
    for(int j=0;j<4;j++){
      float vb = bf2f(pu[r*20+j]);
      if(vb==vb && vb>=0.f && vb<=lims[j] && fabsf(vb-rintf(vb))<0.01f) sb++;
      float vf = pf[r*20+j];
      if(vf==vf && vf>=0.f && vf<=lims[j] && fabsf(vf-rintf(vf))<0.01f) sf++;
    }
  }
  diag[0] = (sf>sb) ? 1 : 0;
  diag[1] = zero;
  diag[2] = sb;
  diag[3] = sf;
}

// ---- post-hoc invariant marker: touches d_out ONLY on failure ----
__global__ void k_marker(const int* __restrict__ diag, const int* __restrict__ rowstart,
                         const float* __restrict__ h, void* __restrict__ out, int N, int Et){
  if(threadIdx.x!=0 || blockIdx.x!=0) return;
  float M = 0.f;
  if(diag[1]) M = 200.f;                            // nodes buffer reads as zeros
  else if(diag[2] < 24 && diag[3] < 24) M = 300.f;  // neither bf16 nor f32 plausible
  else if(rowstart[N] != Et) M = 400.f;             // CSR broken
  else {
    int allz = 1;
    for(int i=0;i<128;i++) if(h[i]!=0.f){ allz=0; break; }
    if(allz) M = 500.f;                             // embed+proj produced nothing
  }
  if(M != 0.f){
    if(diag[0]) ((float*)out)[0] = M;
    else        ((u16*)out)[0]   = f2bf(M);
  }
}

// ---- zero counts[N] and relmean[16] ----
__global__ void k_zero(int* __restrict__ counts, float* __restrict__ relmean, int N){
  int i = blockIdx.x*blockDim.x + threadIdx.x;
  if(i < N) counts[i] = 0;
  if(i < 16) relmean[i] = 0.f;
}

// ---- relation mean over E rows of 16 ----
__global__ void k_relmean(const void* __restrict__ rel, const int* __restrict__ diag,
                          float* __restrict__ relmean, int E){
  const int mode = diag[0];
  __shared__ float red[256][16];
  float s[16];
#pragma unroll
  for(int j=0;j<16;j++) s[j]=0.f;
  for(int r = blockIdx.x*blockDim.x + threadIdx.x; r < E; r += gridDim.x*blockDim.x){
    size_t base = (size_t)r*16;
#pragma unroll
    for(int j=0;j<16;j++) s[j] += ldf(rel, base+j, mode);
  }
  int tid = threadIdx.x;
#pragma unroll
  for(int j=0;j<16;j++) red[tid][j]=s[j];
  __syncthreads();
  for(int off=128; off>0; off>>=1){
    if(tid<off){
#pragma unroll
      for(int j=0;j<16;j++) red[tid][j]+=red[tid+off][j];
    }
    __syncthreads();
  }
  if(tid<16) atomicAdd(relmean+tid, red[0][tid]*(1.0f/(float)E));
}

// ---- CSR build ----
__global__ void k_count(const int* __restrict__ edges, int* __restrict__ counts, int E, int N){
  int Et = E + N;
  int e = blockIdx.x*blockDim.x + threadIdx.x;
  if(e>=Et) return;
  int d = (e<E) ? edges[E+e] : (e-E);
  if(d<0) d=0; if(d>=N) d=N-1;
  atomicAdd(counts+d, 1);
}

__global__ void k_scan(const int* __restrict__ counts, int* __restrict__ rowstart,
                       int* __restrict__ cursor, int N){
  __shared__ int part[1024];
  int tid = threadIdx.x;
  int chunk = (N + 1023) >> 10;
  int lo = tid*chunk, hi = lo+chunk; if(hi>N) hi=N; if(lo>N) lo=N;
  int s=0;
  for(int i=lo;i<hi;i++) s += counts[i];
  part[tid]=s;
  __syncthreads();
  for(int off=1; off<1024; off<<=1){
    int v = (tid>=off) ? part[tid-off] : 0;
    __syncthreads();
    part[tid] += v;
    __syncthreads();
  }
  int run = (tid==0) ? 0 : part[tid-1];
  for(int i=lo;i<hi;i++){ rowstart[i]=run; cursor[i]=run; run += counts[i]; }
  if(tid==1023) rowstart[N] = part[1023];
}

__global__ void k_scatter(const int* __restrict__ edges, int* __restrict__ cursor,
                          int* __restrict__ adj_src, int* __restrict__ adj_eid, int E, int N){
  int Et = E + N;
  int e = blockIdx.x*blockDim.x + threadIdx.x;
  if(e>=Et) return;
  int s, d;
  if(e<E){ s=edges[e]; d=edges[E+e]; } else { s=e-E; d=s; }
  if(d<0) d=0; if(d>=N) d=N-1;
  int pos = atomicAdd(cursor+d, 1);
  adj_src[pos]=s; adj_eid[pos]=e;
}

// ---- embedding + input projection: h[N][64] (f32) ----
__global__ void k_embed(const void* __restrict__ nodes,
                        const void* __restrict__ time_emb, const void* __restrict__ type_emb,
                        const void* __restrict__ biway_emb, const void* __restrict__ islink_emb,
                        const void* __restrict__ projw, const void* __restrict__ projb,
                        const int* __restrict__ diag, float* __restrict__ h, int N){
  const int mode = diag[0];
  __shared__ float W[64][65];
  __shared__ float h0[4][64];
  int tid = threadIdx.x;
  for(int i=tid; i<64*64; i+=256){ W[i>>6][i&63] = ldf(projw, i, mode); }
  __syncthreads();
  int wave = tid>>6, lane = tid&63;
  int node = blockIdx.x*4 + wave;
  if(node<N){
    size_t nr = (size_t)node*20;
    float v; int c = lane;
    if(c<16){
      int t=(int)ldf(nodes,nr+0,mode); t = t<0?0:(t>287?287:t);
      v = ldf(time_emb, t*16+c, mode);
    } else if(c<32){
      int ty=(int)ldf(nodes,nr+1,mode); ty = ty<0?0:(ty>15?15:ty);
      v = ldf(type_emb, ty*16+(c-16), mode);
    } else if(c<40){
      int bw=(int)ldf(nodes,nr+2,mode); bw = bw<0?0:(bw>1?1:bw);
      v = ldf(biway_emb, bw*8+(c-32), mode);
    } else if(c<48){
      int il=(int)ldf(nodes,nr+3,mode); il = il<0?0:(il>1?1:il);
      v = ldf(islink_emb, il*8+(c-40), mode);
    } else {
      v = ldf(nodes, nr+4+(c-48), mode);
    }
    h0[wave][lane]=v;
  }
  __syncthreads();
  if(node<N){
    float acc = ldf(projb, lane, mode);
#pragma unroll
    for(int k=0;k<64;k++) acc += W[lane][k]*h0[wave][k];
    h[(size_t)node*64+lane]=acc;
  }
}

// ---- xl/xr = h @ {wl,wr}.T + {bl,br}  (stored bf16 internally) ----
// weight/bias pointers are BASE pointers; ofsW/ofsB are ELEMENT offsets for layer l
__global__ void k_xlr(const float* __restrict__ h,
                      const void* __restrict__ wl, const void* __restrict__ bl,
                      const void* __restrict__ wr, const void* __restrict__ br,
                      size_t ofsW, size_t ofsB,
                      const int* __restrict__ diag,
                      u16* __restrict__ xl, u16* __restrict__ xr, int N){
  const int mode = diag[0];
  __shared__ float hs[8][64];
  int tid = threadIdx.x;
  int base = blockIdx.x*8;
  for(int i=tid;i<8*64;i+=256){
    int n=i>>6, k=i&63;
    hs[n][k] = (base+n<N) ? h[(size_t)(base+n)*64+k] : 0.f;
  }
  __syncthreads();
  int o = tid;
  float accl[8], accr[8];
  float blv = ldf(bl,ofsB+o,mode), brv = ldf(br,ofsB+o,mode);
#pragma unroll
  for(int n=0;n<8;n++){ accl[n]=blv; accr[n]=brv; }
  for(int k=0;k<64;k++){
    float wlv = ldf(wl,ofsW+(size_t)o*64+k,mode);
    float wrv = ldf(wr,ofsW+(size_t)o*64+k,mode);
#pragma unroll
    for(int n=0;n<8;n++){ float hv=hs[n][k]; accl[n]+=wlv*hv; accr[n]+=wrv*hv; }
  }
  for(int n=0;n<8;n++){
    if(base+n<N){
      xl[(size_t)(base+n)*HHID+o]=f2bf(accl[n]);
      xr[(size_t)(base+n)*HHID+o]=f2bf(accr[n]);
    }
  }
}

// ---- per-edge logits (one wave per edge) ----
__global__ void k_edge(const int* __restrict__ edges, const void* __restrict__ relation,
                       const float* __restrict__ relmean,
                       const void* __restrict__ we, const void* __restrict__ att,
                       size_t ofsWe, size_t ofsAtt,
                       const int* __restrict__ diag,
                       const u16* __restrict__ xl, const u16* __restrict__ xr,
                       float* __restrict__ logits, int E, int N){
  const int mode = diag[0];
  int Et = E + N;
  int wave = threadIdx.x>>6, lane = threadIdx.x&63;
  int e = blockIdx.x*4 + wave;
  if(e>=Et) return;
  int s, d;
  float rel[16];
  if(e<E){
    s=edges[e]; d=edges[E+e];
    size_t base=(size_t)e*16;
#pragma unroll
    for(int j=0;j<16;j++) rel[j]=ldf(relation, base+j, mode);
  } else {
    s=e-E; d=s;
#pragma unroll
    for(int j=0;j<16;j++) rel[j]=relmean[j];
  }
  if(s<0)s=0; if(s>=N)s=N-1; if(d<0)d=0; if(d>=N)d=N-1;
  const u16* xls = xl + (size_t)s*HHID;
  const u16* xrd = xr + (size_t)d*HHID;
  float lg0=0.f, lg1=0.f, lg2=0.f, lg3=0.f;
#pragma unroll
  for(int hh=0; hh<4; hh++){
    int idx = hh*64 + lane;
    float ep = 0.f;
    size_t wbase = ofsWe + (size_t)idx*16;
#pragma unroll
    for(int j=0;j<16;j++) ep += ldf(we, wbase+j, mode)*rel[j];
    float m = bf2f(xls[idx]) + bf2f(xrd[idx]) + ep;
    m = (m>0.f) ? m : 0.2f*m;
    float c = m * ldf(att, ofsAtt + hh*64+lane, mode);
#pragma unroll
    for(int off=32; off>0; off>>=1) c += __shfl_xor(c, off, 64);
    if(hh==0) lg0=c; else if(hh==1) lg1=c; else if(hh==2) lg2=c; else lg3=c;
  }
  if(lane==0){
    float4* lp = (float4*)(logits + (size_t)e*4);
    *lp = make_float4(lg0,lg1,lg2,lg3);
  }
}

// ---- per-node softmax + aggregation + residual (one wave per node) ----
__global__ void k_gather(const int* __restrict__ rowstart, const int* __restrict__ adj_src,
                         const int* __restrict__ adj_eid, const float* __restrict__ logits,
                         const u16* __restrict__ xl, const void* __restrict__ gat_b, size_t ofsB,
                         const int* __restrict__ diag,
                         float* __restrict__ h, int N, void* __restrict__ outp){
  const int mode = diag[0];
  int wave = threadIdx.x>>6, lane = threadIdx.x&63;
  int node = blockIdx.x*4 + wave;
  if(node>=N) return;
  int lo = rowstart[node], hi = rowstart[node+1];
  float mx0=-1e30f, mx1=-1e30f, mx2=-1e30f, mx3=-1e30f;
  for(int p=lo;p<hi;p++){
    int eid = adj_eid[p];
    float4 lg = *(const float4*)(logits + (size_t)eid*4);
    mx0=fmaxf(mx0,lg.x); mx1=fmaxf(mx1,lg.y); mx2=fmaxf(mx2,lg.z); mx3=fmaxf(mx3,lg.w);
  }
  float den0=0.f,den1=0.f,den2=0.f,den3=0.f;
  float acc0=0.f,acc1=0.f,acc2=0.f,acc3=0.f;
  for(int p=lo;p<hi;p++){
    int eid = adj_eid[p];
    int s   = adj_src[p];
    if(s<0)s=0; if(s>=N)s=N-1;
    float4 lg = *(const float4*)(logits + (size_t)eid*4);
    float w0=__expf(lg.x-mx0), w1=__expf(lg.y-mx1), w2=__expf(lg.z-mx2), w3=__expf(lg.w-mx3);
    den0+=w0; den1+=w1; den2+=w2; den3+=w3;
    const u16* xs = xl + (size_t)s*HHID;
    acc0 += w0*bf2f(xs[lane]);
    acc1 += w1*bf2f(xs[64+lane]);
    acc2 += w2*bf2f(xs[128+lane]);
    acc3 += w3*bf2f(xs[192+lane]);
  }
  float outv = 0.25f*(acc0/den0 + acc1/den1 + acc2/den2 + acc3/den3);
  float res = outv + ldf(gat_b, ofsB+lane, mode) + h[(size_t)node*64+lane];
  res = fmaxf(res, 0.f);
  h[(size_t)node*64+lane] = res;
  if(outp){
    if(mode) ((float*)outp)[(size_t)node*64+lane] = res;
    else     ((u16*)outp)[(size_t)node*64+lane]   = f2bf(res);
  }
}

extern "C" void kernel_launch(void* const* d_in, const int* in_sizes, int n_in,
                              void* d_out, int out_size, void* d_ws, size_t ws_size,
                              hipStream_t stream) {
  if(n_in < 16){
    TopoAggregator_33217277067466_kernel<<<2048, 256, 0, stream>>>(
        (u16*)d_out, out_size, (u16)0x0000, (u16)0x4316);   // marker ~150
    return;
  }
  const void* nodes     = d_in[0];
  const int*  edges     = (const int*)d_in[1];
  const void* relation  = d_in[2];
  const void* time_emb  = d_in[3];
  const void* type_emb  = d_in[4];
  const void* biway_emb = d_in[5];
  const void* islink_emb= d_in[6];
  const void* proj_w    = d_in[7];
  const void* proj_b    = d_in[8];
  const void* lin_l_w   = d_in[9];
  const void* lin_l_b   = d_in[10];
  const void* lin_r_w   = d_in[11];
  const void* lin_r_b   = d_in[12];
  const void* lin_e_w   = d_in[13];
  const void* att       = d_in[14];
  const void* gat_b     = d_in[15];

  const int N  = in_sizes[0] / 20;
  const int E  = in_sizes[1] / 2;
  const int Et = E + N;

  size_t off = 0;
  auto alloc = [&](size_t bytes)->size_t {
    size_t p = off;
    off += ((bytes + 255) / 256) * 256;
    return p;
  };
  size_t o_diag     = alloc(256);
  size_t o_h        = alloc((size_t)N*64*4);
  size_t o_xl       = alloc((size_t)N*HHID*2);
  size_t o_xr       = alloc((size_t)N*HHID*2);
  size_t o_logits   = alloc((size_t)Et*4*4);
  size_t o_relmean  = alloc(64*4);
  size_t o_counts   = alloc((size_t)N*4);
  size_t o_rowstart = alloc((size_t)(N+1)*4);
  size_t o_cursor   = alloc((size_t)(N+1)*4);
  size_t o_adjsrc   = alloc((size_t)Et*4);
  size_t o_adjeid   = alloc((size_t)Et*4);

  if (off > ws_size) {
    TopoAggregator_33217277067466_kernel<<<2048, 256, 0, stream>>>(
        (u16*)d_out, out_size, (u16)0x0000, (u16)0x42C8);   // marker ~100
    return;
  }

  char* w = (char*)d_ws;
  int*   diag     = (int*)(w + o_diag);
  float* h        = (float*)(w + o_h);
  u16*   xl       = (u16*)(w + o_xl);
  u16*   xr       = (u16*)(w + o_xr);
  float* logits   = (float*)(w + o_logits);
  float* relmean  = (float*)(w + o_relmean);
  int*   counts   = (int*)(w + o_counts);
  int*   rowstart = (int*)(w + o_rowstart);
  int*   cursor   = (int*)(w + o_cursor);
  int*   adj_src  = (int*)(w + o_adjsrc);
  int*   adj_eid  = (int*)(w + o_adjeid);

  k_detect<<<1, 64, 0, stream>>>(nodes, diag);
  k_zero<<<(N+255)/256, 256, 0, stream>>>(counts, relmean, N);
  k_relmean<<<64, 256, 0, stream>>>(relation, diag, relmean, E);
  k_count<<<(Et+255)/256, 256, 0, stream>>>(edges, counts, E, N);
  k_scan<<<1, 1024, 0, stream>>>(counts, rowstart, cursor, N);
  k_scatter<<<(Et+255)/256, 256, 0, stream>>>(edges, cursor, adj_src, adj_eid, E, N);

  k_embed<<<(N+3)/4, 256, 0, stream>>>(nodes, time_emb, type_emb, biway_emb, islink_emb,
                                       proj_w, proj_b, diag, h, N);

  for(int l=0; l<2; l++){
    k_xlr<<<(N+7)/8, 256, 0, stream>>>(h,
        lin_l_w, lin_l_b, lin_r_w, lin_r_b,
        (size_t)l*HHID*64, (size_t)l*HHID,
        diag, xl, xr, N);
    k_edge<<<(Et+3)/4, 256, 0, stream>>>(edges, relation, relmean,
        lin_e_w, att, (size_t)l*HHID*16, (size_t)l*HEADS*64,
        diag, xl, xr, logits, E, N);
    k_gather<<<(N+3)/4, 256, 0, stream>>>(rowstart, adj_src, adj_eid, logits, xl,
        gat_b, (size_t)l*64, diag, h, N,
        (l==1) ? d_out : (void*)nullptr);
  }
  k_marker<<<1, 64, 0, stream>>>(diag, rowstart, h, d_out, N, Et);
}

// Round 7
// 2816.510 us; speedup vs baseline: 3.6613x; 3.6613x over previous
//
#include <hip/hip_runtime.h>

typedef unsigned short u16;
typedef unsigned int u32;

__device__ __forceinline__ float bf2f(u16 u){ union{u32 i; float f;} v; v.i=((u32)u)<<16; return v.f; }
__device__ __forceinline__ float bflo(u32 p){ union{u32 i; float f;} v; v.i=p<<16; return v.f; }
__device__ __forceinline__ float bfhi(u32 p){ union{u32 i; float f;} v; v.i=p&0xffff0000u; return v.f; }
__device__ __forceinline__ u16 f2bf(float x){ union{float f; u32 i;} v; v.f=x; u32 b=v.i;
  return (u16)((b + 0x7fffu + ((b>>16)&1u))>>16); }

#define HEADS 4
#define HHID 256   // HEADS*HID
#define NT 16      // nodes per block in k_xlr

// ---- fill d_out with a float value (diagnostic only) ----
__global__ void TopoAggregator_33217277067466_kernel(float* __restrict__ out, int n, float val){
  for(int i = blockIdx.x*blockDim.x + threadIdx.x; i < n; i += gridDim.x*blockDim.x)
    out[i] = val;
}

// ---- post-hoc invariant marker: touches d_out ONLY on failure ----
// codes: 400 CSR broken, 700 logits NaN/huge, 500 h all-zero
__global__ void k_marker(const int* __restrict__ rowstart, const float* __restrict__ h,
                         const float* __restrict__ logits, float* __restrict__ out,
                         int N, int Et){
  if(threadIdx.x!=0 || blockIdx.x!=0) return;
  float M = 0.f;
  if(rowstart[N] != Et) M = 400.f;
  else {
    int bad = 0;
    for(int i=0;i<1024;i++){ float v = logits[i]; if(!(v==v) || fabsf(v) > 1e30f){ bad=1; break; } }
    if(bad) M = 700.f;
    else {
      int allz = 1;
      for(int i=0;i<128;i++) if(h[i]!=0.f){ allz=0; break; }
      if(allz) M = 500.f;
    }
  }
  if(M != 0.f) out[0] = M;
}

// ---- zero counts[N] and relmean[16] ----
__global__ void k_zero(int* __restrict__ counts, float* __restrict__ relmean, int N){
  int i = blockIdx.x*blockDim.x + threadIdx.x;
  if(i < N) counts[i] = 0;
  if(i < 16) relmean[i] = 0.f;
}

// ---- relation mean over E rows of 16 (f32) ----
__global__ void k_relmean(const float* __restrict__ rel, float* __restrict__ relmean, int E){
  __shared__ float red[256][16];
  float s[16];
#pragma unroll
  for(int j=0;j<16;j++) s[j]=0.f;
  for(int r = blockIdx.x*blockDim.x + threadIdx.x; r < E; r += gridDim.x*blockDim.x){
    const float4* p = (const float4*)(rel + (size_t)r*16);
    float4 a=p[0], b=p[1], c=p[2], d=p[3];
    s[0]+=a.x; s[1]+=a.y; s[2]+=a.z; s[3]+=a.w;
    s[4]+=b.x; s[5]+=b.y; s[6]+=b.z; s[7]+=b.w;
    s[8]+=c.x; s[9]+=c.y; s[10]+=c.z; s[11]+=c.w;
    s[12]+=d.x; s[13]+=d.y; s[14]+=d.z; s[15]+=d.w;
  }
  int tid = threadIdx.x;
#pragma unroll
  for(int j=0;j<16;j++) red[tid][j]=s[j];
  __syncthreads();
  for(int off=128; off>0; off>>=1){
    if(tid<off){
#pragma unroll
      for(int j=0;j<16;j++) red[tid][j]+=red[tid+off][j];
    }
    __syncthreads();
  }
  if(tid<16) atomicAdd(relmean+tid, red[0][tid]*(1.0f/(float)E));
}

// ---- CSR build ----
__global__ void k_count(const int* __restrict__ edges, int* __restrict__ counts, int E, int N){
  int Et = E + N;
  int e = blockIdx.x*blockDim.x + threadIdx.x;
  if(e>=Et) return;
  int d = (e<E) ? edges[E+e] : (e-E);
  if(d<0) d=0; if(d>=N) d=N-1;
  atomicAdd(counts+d, 1);
}

__global__ void k_scan(const int* __restrict__ counts, int* __restrict__ rowstart,
                       int* __restrict__ cursor, int N){
  __shared__ int part[1024];
  int tid = threadIdx.x;
  int chunk = (N + 1023) >> 10;
  int lo = tid*chunk, hi = lo+chunk; if(hi>N) hi=N; if(lo>N) lo=N;
  int s=0;
  for(int i=lo;i<hi;i++) s += counts[i];
  part[tid]=s;
  __syncthreads();
  for(int off=1; off<1024; off<<=1){
    int v = (tid>=off) ? part[tid-off] : 0;
    __syncthreads();
    part[tid] += v;
    __syncthreads();
  }
  int run = (tid==0) ? 0 : part[tid-1];
  for(int i=lo;i<hi;i++){ rowstart[i]=run; cursor[i]=run; run += counts[i]; }
  if(tid==1023) rowstart[N] = part[1023];
}

__global__ void k_scatter(const int* __restrict__ edges, int* __restrict__ cursor,
                          int* __restrict__ adj_src, int* __restrict__ adj_eid, int E, int N){
  int Et = E + N;
  int e = blockIdx.x*blockDim.x + threadIdx.x;
  if(e>=Et) return;
  int s, d;
  if(e<E){ s=edges[e]; d=edges[E+e]; } else { s=e-E; d=s; }
  if(d<0) d=0; if(d>=N) d=N-1;
  int pos = atomicAdd(cursor+d, 1);
  adj_src[pos]=s; adj_eid[pos]=e;
}

// ---- embedding + input projection: h[N][64] (f32) ----
__global__ void k_embed(const float* __restrict__ nodes,
                        const float* __restrict__ time_emb, const float* __restrict__ type_emb,
                        const float* __restrict__ biway_emb, const float* __restrict__ islink_emb,
                        const float* __restrict__ projw, const float* __restrict__ projb,
                        float* __restrict__ h, int N){
  __shared__ float W[64][65];
  __shared__ float h0[4][64];
  int tid = threadIdx.x;
  for(int i=tid; i<64*64; i+=256) W[i>>6][i&63] = projw[i];
  __syncthreads();
  int wave = tid>>6, lane = tid&63;
  int node = blockIdx.x*4 + wave;
  if(node<N){
    const float* nr = nodes + (size_t)node*20;
    float v; int c = lane;
    if(c<16){
      int t=(int)nr[0]; t = t<0?0:(t>287?287:t);
      v = time_emb[t*16+c];
    } else if(c<32){
      int ty=(int)nr[1]; ty = ty<0?0:(ty>15?15:ty);
      v = type_emb[ty*16+(c-16)];
    } else if(c<40){
      int bw=(int)nr[2]; bw = bw<0?0:(bw>1?1:bw);
      v = biway_emb[bw*8+(c-32)];
    } else if(c<48){
      int il=(int)nr[3]; il = il<0?0:(il>1?1:il);
      v = islink_emb[il*8+(c-40)];
    } else {
      v = nr[4 + (c-48)];
    }
    h0[wave][lane]=v;
  }
  __syncthreads();
  if(node<N){
    float acc = projb[lane];
#pragma unroll
    for(int k=0;k<64;k++) acc += W[lane][k]*h0[wave][k];
    h[(size_t)node*64+lane]=acc;
  }
}

// ---- xl/xr = h @ {wl,wr}.T + {bl,br}, stored bf16. 16 nodes/block ----
// wl/bl/wr/br are pre-offset for the layer on host.
__global__ void k_xlr(const float* __restrict__ h,
                      const float* __restrict__ wl, const float* __restrict__ bl,
                      const float* __restrict__ wr, const float* __restrict__ br,
                      u16* __restrict__ xl, u16* __restrict__ xr, int N){
  __shared__ float hs[NT*64];
  int tid = threadIdx.x;
  int base = blockIdx.x*NT;
  int nvalid = N - base; if(nvalid > NT) nvalid = NT;
  if(nvalid == NT){
    *(float4*)(hs + tid*4) = *(const float4*)(h + (size_t)base*64 + tid*4);
  } else {
    for(int i=tid; i<NT*64; i+=256) hs[i] = (i < nvalid*64) ? h[(size_t)base*64+i] : 0.f;
  }
  __syncthreads();
  int o = tid;   // output channel 0..255
  const float4* wl4 = (const float4*)(wl + (size_t)o*64);
  const float4* wr4 = (const float4*)(wr + (size_t)o*64);
  float blv = bl[o], brv = br[o];
  float accl[NT], accr[NT];
#pragma unroll
  for(int n=0;n<NT;n++){ accl[n]=blv; accr[n]=brv; }
  for(int kk=0; kk<16; kk++){
    float4 a = wl4[kk];
    float4 b = wr4[kk];
#pragma unroll
    for(int n=0;n<NT;n++){
      float4 hv = *(const float4*)(hs + n*64 + kk*4);
      accl[n] += a.x*hv.x + a.y*hv.y + a.z*hv.z + a.w*hv.w;
      accr[n] += b.x*hv.x + b.y*hv.y + b.z*hv.z + b.w*hv.w;
    }
  }
  for(int n=0;n<nvalid;n++){
    xl[(size_t)(base+n)*HHID + o] = f2bf(accl[n]);
    xr[(size_t)(base+n)*HHID + o] = f2bf(accr[n]);
  }
}

// ---- per-edge logits: one wave/edge, lane owns 4 consecutive channels ----
// we/att pre-offset for the layer on host.
__global__ void k_edge(const int* __restrict__ edges, const float* __restrict__ relation,
                       const float* __restrict__ relmean,
                       const float* __restrict__ we, const float* __restrict__ att,
                       const u16* __restrict__ xl, const u16* __restrict__ xr,
                       float* __restrict__ logits, int E, int N){
  const int Et = E + N;
  const int wave = threadIdx.x>>6, lane = threadIdx.x&63;
  const int head = lane>>4;
  const int e = blockIdx.x*4 + wave;
  if(e>=Et) return;

  float at0=att[lane*4+0], at1=att[lane*4+1], at2=att[lane*4+2], at3=att[lane*4+3];

  int s, d;
  float4 r0, r1, r2, r3;
  if(e < E){
    s = edges[e]; d = edges[E+e];
    const float4* rp = (const float4*)(relation + (size_t)e*16);
    r0=rp[0]; r1=rp[1]; r2=rp[2]; r3=rp[3];
  } else {
    s = d = e - E;
    const float4* rp = (const float4*)relmean;
    r0=rp[0]; r1=rp[1]; r2=rp[2]; r3=rp[3];
  }
  if(s<0)s=0; if(s>=N)s=N-1; if(d<0)d=0; if(d>=N)d=N-1;

  uint2 pa = *(const uint2*)(xl + (size_t)s*HHID + lane*4);
  uint2 pb = *(const uint2*)(xr + (size_t)d*HHID + lane*4);
  float av0=bflo(pa.x), av1=bfhi(pa.x), av2=bflo(pa.y), av3=bfhi(pa.y);
  float bv0=bflo(pb.x), bv1=bfhi(pb.x), bv2=bflo(pb.y), bv3=bfhi(pb.y);

  float c = 0.f;
#pragma unroll
  for(int j=0;j<4;j++){
    const float4* w4 = (const float4*)(we + (size_t)(lane*4+j)*16);
    float4 w0=w4[0], w1=w4[1], w2=w4[2], w3=w4[3];
    float ep = r0.x*w0.x + r0.y*w0.y + r0.z*w0.z + r0.w*w0.w
             + r1.x*w1.x + r1.y*w1.y + r1.z*w1.z + r1.w*w1.w
             + r2.x*w2.x + r2.y*w2.y + r2.z*w2.z + r2.w*w2.w
             + r3.x*w3.x + r3.y*w3.y + r3.z*w3.z + r3.w*w3.w;
    float avj = (j==0)?av0:(j==1)?av1:(j==2)?av2:av3;
    float bvj = (j==0)?bv0:(j==1)?bv1:(j==2)?bv2:bv3;
    float m = avj + bvj + ep;
    m = (m>0.f) ? m : 0.2f*m;
    float atj = (j==0)?at0:(j==1)?at1:(j==2)?at2:at3;
    c += m*atj;
  }
  c += __shfl_xor(c, 1);
  c += __shfl_xor(c, 2);
  c += __shfl_xor(c, 4);
  c += __shfl_xor(c, 8);
  if((lane & 15) == 0) logits[(size_t)e*4 + head] = c;
}

// ---- per-node softmax + aggregation + residual; one wave/node, lane owns 4 channels ----
// gat_b pre-offset for the layer on host.
__global__ void k_gather(const int* __restrict__ rowstart, const int* __restrict__ adj_src,
                         const int* __restrict__ adj_eid, const float* __restrict__ logits,
                         const u16* __restrict__ xl, const float* __restrict__ gat_b,
                         float* __restrict__ h, int N, float* __restrict__ outp){
  const int lane = threadIdx.x & 63;
  const int head = lane >> 4, sub = lane & 15;
  int node = blockIdx.x*4 + (threadIdx.x>>6);
  if(node>=N) return;
  const int lo = rowstart[node], hi = rowstart[node+1];

  float mxh = -1e30f;
  for(int p=lo;p<hi;p++){
    int eid = adj_eid[p];
    mxh = fmaxf(mxh, logits[(size_t)eid*4 + head]);
  }
  float den=0.f, a0=0.f, a1=0.f, a2=0.f, a3=0.f;
  for(int p=lo;p<hi;p++){
    int eid = adj_eid[p];
    int sv  = adj_src[p];
    if(sv<0) sv=0; if(sv>=N) sv=N-1;
    float wgt = __expf(logits[(size_t)eid*4 + head] - mxh);
    den += wgt;
    uint2 pr = *(const uint2*)(xl + (size_t)sv*HHID + lane*4);
    a0 += wgt*bflo(pr.x); a1 += wgt*bfhi(pr.x);
    a2 += wgt*bflo(pr.y); a3 += wgt*bfhi(pr.y);
  }
  float inv = 1.0f/den;
  float v0=a0*inv, v1=a1*inv, v2=a2*inv, v3=a3*inv;
  v0 += __shfl_xor(v0,16); v0 += __shfl_xor(v0,32);
  v1 += __shfl_xor(v1,16); v1 += __shfl_xor(v1,32);
  v2 += __shfl_xor(v2,16); v2 += __shfl_xor(v2,32);
  v3 += __shfl_xor(v3,16); v3 += __shfl_xor(v3,32);
  if(lane < 16){
    int cb = sub*4;
    float4 hv = *(const float4*)(h + (size_t)node*64 + cb);
    const float4 gb = *(const float4*)(gat_b + cb);
    float o0 = fmaxf(0.25f*v0 + gb.x + hv.x, 0.f);
    float o1 = fmaxf(0.25f*v1 + gb.y + hv.y, 0.f);
    float o2 = fmaxf(0.25f*v2 + gb.z + hv.z, 0.f);
    float o3 = fmaxf(0.25f*v3 + gb.w + hv.w, 0.f);
    *(float4*)(h + (size_t)node*64 + cb) = make_float4(o0,o1,o2,o3);
    if(outp) *(float4*)(outp + (size_t)node*64 + cb) = make_float4(o0,o1,o2,o3);
  }
}

extern "C" void kernel_launch(void* const* d_in, const int* in_sizes, int n_in,
                              void* d_out, int out_size, void* d_ws, size_t ws_size,
                              hipStream_t stream) {
  const float* nodes     = (const float*)d_in[0];
  const int*   edges     = (const int*)d_in[1];
  const float* relation  = (const float*)d_in[2];
  const float* time_emb  = (const float*)d_in[3];
  const float* type_emb  = (const float*)d_in[4];
  const float* biway_emb = (const float*)d_in[5];
  const float* islink_emb= (const float*)d_in[6];
  const float* proj_w    = (const float*)d_in[7];
  const float* proj_b    = (const float*)d_in[8];
  const float* lin_l_w   = (const float*)d_in[9];
  const float* lin_l_b   = (const float*)d_in[10];
  const float* lin_r_w   = (const float*)d_in[11];
  const float* lin_r_b   = (const float*)d_in[12];
  const float* lin_e_w   = (const float*)d_in[13];
  const float* att       = (const float*)d_in[14];
  const float* gat_b     = (const float*)d_in[15];

  const int N  = in_sizes[0] / 20;
  const int E  = in_sizes[1] / 2;
  const int Et = E + N;

  size_t off = 0;
  auto alloc = [&](size_t bytes)->size_t {
    size_t p = off;
    off += ((bytes + 255) / 256) * 256;
    return p;
  };
  size_t o_h        = alloc((size_t)N*64*4);        // f32
  size_t o_xl       = alloc((size_t)N*HHID*2);      // bf16
  size_t o_xr       = alloc((size_t)N*HHID*2);      // bf16
  size_t o_logits   = alloc((size_t)Et*4*4);        // f32
  size_t o_relmean  = alloc(64*4);
  size_t o_counts   = alloc((size_t)N*4);
  size_t o_rowstart = alloc((size_t)(N+1)*4);
  size_t o_cursor   = alloc((size_t)(N+1)*4);
  size_t o_adjsrc   = alloc((size_t)Et*4);
  size_t o_adjeid   = alloc((size_t)Et*4);

  if (off > ws_size) {
    TopoAggregator_33217277067466_kernel<<<2048, 256, 0, stream>>>(
        (float*)d_out, out_size, 100.0f);   // marker ~100: ws too small
    return;
  }

  char* w = (char*)d_ws;
  float* h        = (float*)(w + o_h);
  u16*   xl       = (u16*)(w + o_xl);
  u16*   xr       = (u16*)(w + o_xr);
  float* logits   = (float*)(w + o_logits);
  float* relmean  = (float*)(w + o_relmean);
  int*   counts   = (int*)(w + o_counts);
  int*   rowstart = (int*)(w + o_rowstart);
  int*   cursor   = (int*)(w + o_cursor);
  int*   adj_src  = (int*)(w + o_adjsrc);
  int*   adj_eid  = (int*)(w + o_adjeid);

  k_zero<<<(N+255)/256, 256, 0, stream>>>(counts, relmean, N);
  k_relmean<<<64, 256, 0, stream>>>(relation, relmean, E);
  k_count<<<(Et+255)/256, 256, 0, stream>>>(edges, counts, E, N);
  k_scan<<<1, 1024, 0, stream>>>(counts, rowstart, cursor, N);
  k_scatter<<<(Et+255)/256, 256, 0, stream>>>(edges, cursor, adj_src, adj_eid, E, N);

  k_embed<<<(N+3)/4, 256, 0, stream>>>(nodes, time_emb, type_emb, biway_emb, islink_emb,
                                       proj_w, proj_b, h, N);

  for(int l=0; l<2; l++){
    k_xlr<<<(N+NT-1)/NT, 256, 0, stream>>>(h,
        lin_l_w + (size_t)l*HHID*64, lin_l_b + (size_t)l*HHID,
        lin_r_w + (size_t)l*HHID*64, lin_r_b + (size_t)l*HHID,
        xl, xr, N);
    k_edge<<<(Et+3)/4, 256, 0, stream>>>(edges, relation, relmean,
        lin_e_w + (size_t)l*HHID*16, att + (size_t)l*HEADS*64,
        xl, xr, logits, E, N);
    k_gather<<<(N+3)/4, 256, 0, stream>>>(rowstart, adj_src, adj_eid, logits, xl,
        gat_b + (size_t)l*64, h, N,
        (l==1) ? (float*)d_out : (float*)nullptr);
  }
  k_marker<<<1, 64, 0, stream>>>(rowstart, h, logits, (float*)d_out, N, Et);
}

// Round 8
// 1591.629 us; speedup vs baseline: 6.4790x; 1.7696x over previous
//
#include <hip/hip_runtime.h>

typedef unsigned short u16;
typedef unsigned int u32;

__device__ __forceinline__ float bf2f(u16 u){ union{u32 i; float f;} v; v.i=((u32)u)<<16; return v.f; }
__device__ __forceinline__ float bflo(u32 p){ union{u32 i; float f;} v; v.i=p<<16; return v.f; }
__device__ __forceinline__ float bfhi(u32 p){ union{u32 i; float f;} v; v.i=p&0xffff0000u; return v.f; }
__device__ __forceinline__ u16 f2bf(float x){ union{float f; u32 i;} v; v.f=x; u32 b=v.i;
  return (u16)((b + 0x7fffu + ((b>>16)&1u))>>16); }

#define HEADS 4
#define HHID 256   // HEADS*HID
#define NT 16      // nodes per block in k_xlr

// ---- fill d_out with a float value (diagnostic only) ----
__global__ void TopoAggregator_33217277067466_kernel(float* __restrict__ out, int n, float val){
  for(int i = blockIdx.x*blockDim.x + threadIdx.x; i < n; i += gridDim.x*blockDim.x)
    out[i] = val;
}

// ---- post-hoc invariant marker: touches d_out ONLY on failure ----
// codes: 400 CSR broken, 700 logits NaN/huge, 500 h all-zero
__global__ void k_marker(const int* __restrict__ rowstart, const float* __restrict__ h,
                         const float* __restrict__ logits, float* __restrict__ out,
                         int N, int Et){
  if(threadIdx.x!=0 || blockIdx.x!=0) return;
  float M = 0.f;
  if(rowstart[N] != Et) M = 400.f;
  else {
    int bad = 0;
    for(int i=0;i<1024;i++){ float v = logits[i]; if(!(v==v) || fabsf(v) > 1e30f){ bad=1; break; } }
    if(bad) M = 700.f;
    else {
      int allz = 1;
      for(int i=0;i<128;i++) if(h[i]!=0.f){ allz=0; break; }
      if(allz) M = 500.f;
    }
  }
  if(M != 0.f) out[0] = M;
}

// ---- zero counts[N] and relmean[16] ----
__global__ void k_zero(int* __restrict__ counts, float* __restrict__ relmean, int N){
  int i = blockIdx.x*blockDim.x + threadIdx.x;
  if(i < N) counts[i] = 0;
  if(i < 16) relmean[i] = 0.f;
}

// ---- relation mean over E rows of 16 (f32) ----
__global__ void k_relmean(const float* __restrict__ rel, float* __restrict__ relmean, int E){
  __shared__ float red[256][16];
  float s[16];
#pragma unroll
  for(int j=0;j<16;j++) s[j]=0.f;
  for(int r = blockIdx.x*blockDim.x + threadIdx.x; r < E; r += gridDim.x*blockDim.x){
    const float4* p = (const float4*)(rel + (size_t)r*16);
    float4 a=p[0], b=p[1], c=p[2], d=p[3];
    s[0]+=a.x; s[1]+=a.y; s[2]+=a.z; s[3]+=a.w;
    s[4]+=b.x; s[5]+=b.y; s[6]+=b.z; s[7]+=b.w;
    s[8]+=c.x; s[9]+=c.y; s[10]+=c.z; s[11]+=c.w;
    s[12]+=d.x; s[13]+=d.y; s[14]+=d.z; s[15]+=d.w;
  }
  int tid = threadIdx.x;
#pragma unroll
  for(int j=0;j<16;j++) red[tid][j]=s[j];
  __syncthreads();
  for(int off=128; off>0; off>>=1){
    if(tid<off){
#pragma unroll
      for(int j=0;j<16;j++) red[tid][j]+=red[tid+off][j];
    }
    __syncthreads();
  }
  if(tid<16) atomicAdd(relmean+tid, red[0][tid]*(1.0f/(float)E));
}

// ---- CSR build ----
__global__ void k_count(const int* __restrict__ edges, int* __restrict__ counts, int E, int N){
  int Et = E + N;
  int e = blockIdx.x*blockDim.x + threadIdx.x;
  if(e>=Et) return;
  int d = (e<E) ? edges[E+e] : (e-E);
  if(d<0) d=0; if(d>=N) d=N-1;
  atomicAdd(counts+d, 1);
}

__global__ void k_scan(const int* __restrict__ counts, int* __restrict__ rowstart,
                       int* __restrict__ cursor, int N){
  __shared__ int part[1024];
  int tid = threadIdx.x;
  int chunk = (N + 1023) >> 10;
  int lo = tid*chunk, hi = lo+chunk; if(hi>N) hi=N; if(lo>N) lo=N;
  int s=0;
  for(int i=lo;i<hi;i++) s += counts[i];
  part[tid]=s;
  __syncthreads();
  for(int off=1; off<1024; off<<=1){
    int v = (tid>=off) ? part[tid-off] : 0;
    __syncthreads();
    part[tid] += v;
    __syncthreads();
  }
  int run = (tid==0) ? 0 : part[tid-1];
  for(int i=lo;i<hi;i++){ rowstart[i]=run; cursor[i]=run; run += counts[i]; }
  if(tid==1023) rowstart[N] = part[1023];
}

__global__ void k_scatter(const int* __restrict__ edges, int* __restrict__ cursor,
                          int* __restrict__ adj_src, int* __restrict__ adj_eid, int E, int N){
  int Et = E + N;
  int e = blockIdx.x*blockDim.x + threadIdx.x;
  if(e>=Et) return;
  int s, d;
  if(e<E){ s=edges[e]; d=edges[E+e]; } else { s=e-E; d=s; }
  if(d<0) d=0; if(d>=N) d=N-1;
  int pos = atomicAdd(cursor+d, 1);
  adj_src[pos]=s; adj_eid[pos]=e;
}

// ---- embedding + input projection: h[N][64] (f32) ----
__global__ void k_embed(const float* __restrict__ nodes,
                        const float* __restrict__ time_emb, const float* __restrict__ type_emb,
                        const float* __restrict__ biway_emb, const float* __restrict__ islink_emb,
                        const float* __restrict__ projw, const float* __restrict__ projb,
                        float* __restrict__ h, int N){
  __shared__ float W[64][65];
  __shared__ float h0[4][64];
  int tid = threadIdx.x;
  for(int i=tid; i<64*64; i+=256) W[i>>6][i&63] = projw[i];
  __syncthreads();
  int wave = tid>>6, lane = tid&63;
  int node = blockIdx.x*4 + wave;
  if(node<N){
    const float* nr = nodes + (size_t)node*20;
    float v; int c = lane;
    if(c<16){
      int t=(int)nr[0]; t = t<0?0:(t>287?287:t);
      v = time_emb[t*16+c];
    } else if(c<32){
      int ty=(int)nr[1]; ty = ty<0?0:(ty>15?15:ty);
      v = type_emb[ty*16+(c-16)];
    } else if(c<40){
      int bw=(int)nr[2]; bw = bw<0?0:(bw>1?1:bw);
      v = biway_emb[bw*8+(c-32)];
    } else if(c<48){
      int il=(int)nr[3]; il = il<0?0:(il>1?1:il);
      v = islink_emb[il*8+(c-40)];
    } else {
      v = nr[4 + (c-48)];
    }
    h0[wave][lane]=v;
  }
  __syncthreads();
  if(node<N){
    float acc = projb[lane];
#pragma unroll
    for(int k=0;k<64;k++) acc += W[lane][k]*h0[wave][k];
    h[(size_t)node*64+lane]=acc;
  }
}

// ---- xl/xr = h @ {wl,wr}.T + {bl,br}, stored bf16. 16 nodes/block ----
__global__ void k_xlr(const float* __restrict__ h,
                      const float* __restrict__ wl, const float* __restrict__ bl,
                      const float* __restrict__ wr, const float* __restrict__ br,
                      u16* __restrict__ xl, u16* __restrict__ xr, int N){
  __shared__ float hs[NT*64];
  int tid = threadIdx.x;
  int base = blockIdx.x*NT;
  int nvalid = N - base; if(nvalid > NT) nvalid = NT;
  if(nvalid == NT){
    *(float4*)(hs + tid*4) = *(const float4*)(h + (size_t)base*64 + tid*4);
  } else {
    for(int i=tid; i<NT*64; i+=256) hs[i] = (i < nvalid*64) ? h[(size_t)base*64+i] : 0.f;
  }
  __syncthreads();
  int o = tid;   // output channel 0..255
  const float4* wl4 = (const float4*)(wl + (size_t)o*64);
  const float4* wr4 = (const float4*)(wr + (size_t)o*64);
  float blv = bl[o], brv = br[o];
  float accl[NT], accr[NT];
#pragma unroll
  for(int n=0;n<NT;n++){ accl[n]=blv; accr[n]=brv; }
  for(int kk=0; kk<16; kk++){
    float4 a = wl4[kk];
    float4 b = wr4[kk];
#pragma unroll
    for(int n=0;n<NT;n++){
      float4 hv = *(const float4*)(hs + n*64 + kk*4);
      accl[n] += a.x*hv.x + a.y*hv.y + a.z*hv.z + a.w*hv.w;
      accr[n] += b.x*hv.x + b.y*hv.y + b.z*hv.z + b.w*hv.w;
    }
  }
  for(int n=0;n<nvalid;n++){
    xl[(size_t)(base+n)*HHID + o] = f2bf(accl[n]);
    xr[(size_t)(base+n)*HHID + o] = f2bf(accr[n]);
  }
}

// ---- per-edge logits: persistent waves, grid-stride, 2-stage pipeline ----
// we/att pre-offset for the layer on host. Lane owns 4 consecutive channels.
__global__ void k_edge(const int* __restrict__ edges, const float* __restrict__ relation,
                       const float* __restrict__ relmean,
                       const float* __restrict__ we, const float* __restrict__ att,
                       const u16* __restrict__ xl, const u16* __restrict__ xr,
                       float* __restrict__ logits, int E, int N){
  const int Et = E + N;
  const int lane = threadIdx.x & 63;
  const int head = lane >> 4;
  const int wid = (blockIdx.x*blockDim.x + threadIdx.x) >> 6;
  const int nw  = (gridDim.x*blockDim.x) >> 6;

  // hoist: this lane's 4 weight rows = 64 contiguous floats, and att quad
  float wreg[64];
  {
    const float4* wp = (const float4*)(we + (size_t)lane*64);
#pragma unroll
    for(int i=0;i<16;i++){
      float4 t = wp[i];
      wreg[i*4+0]=t.x; wreg[i*4+1]=t.y; wreg[i*4+2]=t.z; wreg[i*4+3]=t.w;
    }
  }
  const float4 at4 = *(const float4*)(att + lane*4);

  int e = wid;
  if(e >= Et) return;

  // prologue: idx(e) -> data(e); idx(e+nw)
  int sc, dc;
  if(e < E){ sc = edges[e]; dc = edges[E+e]; } else { sc = dc = e - E; }
  if(sc<0)sc=0; if(sc>=N)sc=N-1; if(dc<0)dc=0; if(dc>=N)dc=N-1;

  float rc[16];
  {
    const float4* rp = (e < E) ? (const float4*)(relation + (size_t)e*16)
                               : (const float4*)relmean;
    float4 q0=rp[0], q1=rp[1], q2=rp[2], q3=rp[3];
    rc[0]=q0.x; rc[1]=q0.y; rc[2]=q0.z; rc[3]=q0.w;
    rc[4]=q1.x; rc[5]=q1.y; rc[6]=q1.z; rc[7]=q1.w;
    rc[8]=q2.x; rc[9]=q2.y; rc[10]=q2.z; rc[11]=q2.w;
    rc[12]=q3.x; rc[13]=q3.y; rc[14]=q3.z; rc[15]=q3.w;
  }
  uint2 pac = *(const uint2*)(xl + (size_t)sc*HHID + lane*4);
  uint2 pbc = *(const uint2*)(xr + (size_t)dc*HHID + lane*4);

  int en = e + nw;
  int sn=0, dn=0;
  if(en < Et){
    if(en < E){ sn = edges[en]; dn = edges[E+en]; } else { sn = dn = en - E; }
    if(sn<0)sn=0; if(sn>=N)sn=N-1; if(dn<0)dn=0; if(dn>=N)dn=N-1;
  }

  while(true){
    // stage 1: issue data loads for en (idx already resident)
    float rn[16]; uint2 pan, pbn;
    if(en < Et){
      const float4* rp = (en < E) ? (const float4*)(relation + (size_t)en*16)
                                  : (const float4*)relmean;
      float4 q0=rp[0], q1=rp[1], q2=rp[2], q3=rp[3];
      rn[0]=q0.x; rn[1]=q0.y; rn[2]=q0.z; rn[3]=q0.w;
      rn[4]=q1.x; rn[5]=q1.y; rn[6]=q1.z; rn[7]=q1.w;
      rn[8]=q2.x; rn[9]=q2.y; rn[10]=q2.z; rn[11]=q2.w;
      rn[12]=q3.x; rn[13]=q3.y; rn[14]=q3.z; rn[15]=q3.w;
      pan = *(const uint2*)(xl + (size_t)sn*HHID + lane*4);
      pbn = *(const uint2*)(xr + (size_t)dn*HHID + lane*4);
    }
    // stage 2: issue idx loads for en+nw
    int e2 = en + nw;
    int s2=0, d2=0;
    if(e2 < Et){
      if(e2 < E){ s2 = edges[e2]; d2 = edges[E+e2]; } else { s2 = d2 = e2 - E; }
      if(s2<0)s2=0; if(s2>=N)s2=N-1; if(d2<0)d2=0; if(d2>=N)d2=N-1;
    }

    // stage 3: compute current edge e (data resident)
    float c = 0.f;
    {
      float av0=bflo(pac.x), av1=bfhi(pac.x), av2=bflo(pac.y), av3=bfhi(pac.y);
      float bv0=bflo(pbc.x), bv1=bfhi(pbc.x), bv2=bflo(pbc.y), bv3=bfhi(pbc.y);
#pragma unroll
      for(int j=0;j<4;j++){
        float ep = 0.f;
#pragma unroll
        for(int k=0;k<16;k++) ep += rc[k]*wreg[j*16+k];
        float avj = (j==0)?av0:(j==1)?av1:(j==2)?av2:av3;
        float bvj = (j==0)?bv0:(j==1)?bv1:(j==2)?bv2:bv3;
        float m = avj + bvj + ep;
        m = (m>0.f) ? m : 0.2f*m;
        float atj = (j==0)?at4.x:(j==1)?at4.y:(j==2)?at4.z:at4.w;
        c += m*atj;
      }
    }
    c += __shfl_xor(c, 1);
    c += __shfl_xor(c, 2);
    c += __shfl_xor(c, 4);
    c += __shfl_xor(c, 8);
    if((lane & 15) == 0) logits[(size_t)e*4 + head] = c;

    if(en >= Et) break;
    // rotate pipeline registers
    e = en; en = e2;
    sn = s2; dn = d2;
#pragma unroll
    for(int k=0;k<16;k++) rc[k]=rn[k];
    pac = pan; pbc = pbn;
  }
}

// ---- per-node softmax + aggregation + residual; one wave/node, lane owns 4 channels ----
__global__ void k_gather(const int* __restrict__ rowstart, const int* __restrict__ adj_src,
                         const int* __restrict__ adj_eid, const float* __restrict__ logits,
                         const u16* __restrict__ xl, const float* __restrict__ gat_b,
                         float* __restrict__ h, int N, float* __restrict__ outp){
  const int lane = threadIdx.x & 63;
  const int head = lane >> 4, sub = lane & 15;
  int node = blockIdx.x*4 + (threadIdx.x>>6);
  if(node>=N) return;
  const int lo = rowstart[node], hi = rowstart[node+1];

  float mxh = -1e30f;
  for(int p=lo;p<hi;p++){
    int eid = adj_eid[p];
    mxh = fmaxf(mxh, logits[(size_t)eid*4 + head]);
  }
  float den=0.f, a0=0.f, a1=0.f, a2=0.f, a3=0.f;
  for(int p=lo;p<hi;p++){
    int eid = adj_eid[p];
    int sv  = adj_src[p];
    if(sv<0) sv=0; if(sv>=N) sv=N-1;
    float wgt = __expf(logits[(size_t)eid*4 + head] - mxh);
    den += wgt;
    uint2 pr = *(const uint2*)(xl + (size_t)sv*HHID + lane*4);
    a0 += wgt*bflo(pr.x); a1 += wgt*bfhi(pr.x);
    a2 += wgt*bflo(pr.y); a3 += wgt*bfhi(pr.y);
  }
  float inv = 1.0f/den;
  float v0=a0*inv, v1=a1*inv, v2=a2*inv, v3=a3*inv;
  v0 += __shfl_xor(v0,16); v0 += __shfl_xor(v0,32);
  v1 += __shfl_xor(v1,16); v1 += __shfl_xor(v1,32);
  v2 += __shfl_xor(v2,16); v2 += __shfl_xor(v2,32);
  v3 += __shfl_xor(v3,16); v3 += __shfl_xor(v3,32);
  if(lane < 16){
    int cb = sub*4;
    float4 hv = *(const float4*)(h + (size_t)node*64 + cb);
    const float4 gb = *(const float4*)(gat_b + cb);
    float o0 = fmaxf(0.25f*v0 + gb.x + hv.x, 0.f);
    float o1 = fmaxf(0.25f*v1 + gb.y + hv.y, 0.f);
    float o2 = fmaxf(0.25f*v2 + gb.z + hv.z, 0.f);
    float o3 = fmaxf(0.25f*v3 + gb.w + hv.w, 0.f);
    *(float4*)(h + (size_t)node*64 + cb) = make_float4(o0,o1,o2,o3);
    if(outp) *(float4*)(outp + (size_t)node*64 + cb) = make_float4(o0,o1,o2,o3);
  }
}

extern "C" void kernel_launch(void* const* d_in, const int* in_sizes, int n_in,
                              void* d_out, int out_size, void* d_ws, size_t ws_size,
                              hipStream_t stream) {
  const float* nodes     = (const float*)d_in[0];
  const int*   edges     = (const int*)d_in[1];
  const float* relation  = (const float*)d_in[2];
  const float* time_emb  = (const float*)d_in[3];
  const float* type_emb  = (const float*)d_in[4];
  const float* biway_emb = (const float*)d_in[5];
  const float* islink_emb= (const float*)d_in[6];
  const float* proj_w    = (const float*)d_in[7];
  const float* proj_b    = (const float*)d_in[8];
  const float* lin_l_w   = (const float*)d_in[9];
  const float* lin_l_b   = (const float*)d_in[10];
  const float* lin_r_w   = (const float*)d_in[11];
  const float* lin_r_b   = (const float*)d_in[12];
  const float* lin_e_w   = (const float*)d_in[13];
  const float* att       = (const float*)d_in[14];
  const float* gat_b     = (const float*)d_in[15];

  const int N  = in_sizes[0] / 20;
  const int E  = in_sizes[1] / 2;
  const int Et = E + N;

  size_t off = 0;
  auto alloc = [&](size_t bytes)->size_t {
    size_t p = off;
    off += ((bytes + 255) / 256) * 256;
    return p;
  };
  size_t o_h        = alloc((size_t)N*64*4);        // f32
  size_t o_xl       = alloc((size_t)N*HHID*2);      // bf16
  size_t o_xr       = alloc((size_t)N*HHID*2);      // bf16
  size_t o_logits   = alloc((size_t)Et*4*4);        // f32
  size_t o_relmean  = alloc(64*4);
  size_t o_counts   = alloc((size_t)N*4);
  size_t o_rowstart = alloc((size_t)(N+1)*4);
  size_t o_cursor   = alloc((size_t)(N+1)*4);
  size_t o_adjsrc   = alloc((size_t)Et*4);
  size_t o_adjeid   = alloc((size_t)Et*4);

  if (off > ws_size) {
    TopoAggregator_33217277067466_kernel<<<2048, 256, 0, stream>>>(
        (float*)d_out, out_size, 100.0f);   // marker ~100: ws too small
    return;
  }

  char* w = (char*)d_ws;
  float* h        = (float*)(w + o_h);
  u16*   xl       = (u16*)(w + o_xl);
  u16*   xr       = (u16*)(w + o_xr);
  float* logits   = (float*)(w + o_logits);
  float* relmean  = (float*)(w + o_relmean);
  int*   counts   = (int*)(w + o_counts);
  int*   rowstart = (int*)(w + o_rowstart);
  int*   cursor   = (int*)(w + o_cursor);
  int*   adj_src  = (int*)(w + o_adjsrc);
  int*   adj_eid  = (int*)(w + o_adjeid);

  k_zero<<<(N+255)/256, 256, 0, stream>>>(counts, relmean, N);
  k_relmean<<<64, 256, 0, stream>>>(relation, relmean, E);
  k_count<<<(Et+255)/256, 256, 0, stream>>>(edges, counts, E, N);
  k_scan<<<1, 1024, 0, stream>>>(counts, rowstart, cursor, N);
  k_scatter<<<(Et+255)/256, 256, 0, stream>>>(edges, cursor, adj_src, adj_eid, E, N);

  k_embed<<<(N+3)/4, 256, 0, stream>>>(nodes, time_emb, type_emb, biway_emb, islink_emb,
                                       proj_w, proj_b, h, N);

  for(int l=0; l<2; l++){
    k_xlr<<<(N+NT-1)/NT, 256, 0, stream>>>(h,
        lin_l_w + (size_t)l*HHID*64, lin_l_b + (size_t)l*HHID,
        lin_r_w + (size_t)l*HHID*64, lin_r_b + (size_t)l*HHID,
        xl, xr, N);
    k_edge<<<4096, 256, 0, stream>>>(edges, relation, relmean,
        lin_e_w + (size_t)l*HHID*16, att + (size_t)l*HEADS*64,
        xl, xr, logits, E, N);
    k_gather<<<(N+3)/4, 256, 0, stream>>>(rowstart, adj_src, adj_eid, logits, xl,
        gat_b + (size_t)l*64, h, N,
        (l==1) ? (float*)d_out : (float*)nullptr);
  }
  k_marker<<<1, 64, 0, stream>>>(rowstart, h, logits, (float*)d_out, N, Et);
}

// Round 9
// 1188.867 us; speedup vs baseline: 8.6739x; 1.3388x over previous
//
#include <hip/hip_runtime.h>

typedef unsigned short u16;
typedef unsigned int u32;

__device__ __forceinline__ float bf2f(u16 u){ union{u32 i; float f;} v; v.i=((u32)u)<<16; return v.f; }
__device__ __forceinline__ float bflo(u32 p){ union{u32 i; float f;} v; v.i=p<<16; return v.f; }
__device__ __forceinline__ float bfhi(u32 p){ union{u32 i; float f;} v; v.i=p&0xffff0000u; return v.f; }
__device__ __forceinline__ u16 f2bf(float x){ union{float f; u32 i;} v; v.f=x; u32 b=v.i;
  return (u16)((b + 0x7fffu + ((b>>16)&1u))>>16); }

#define HEADS 4
#define HHID 256   // HEADS*HID
#define NT 16      // nodes per block in k_xlr

// ---- fill d_out with a float value (diagnostic only) ----
__global__ void TopoAggregator_33217277067466_kernel(float* __restrict__ out, int n, float val){
  for(int i = blockIdx.x*blockDim.x + threadIdx.x; i < n; i += gridDim.x*blockDim.x)
    out[i] = val;
}

// ---- post-hoc invariant marker: touches d_out ONLY on failure ----
// codes: 400 CSR broken, 500 h all-zero
__global__ void k_marker(const int* __restrict__ rowstart, const float* __restrict__ h,
                         float* __restrict__ out, int N, int Et){
  if(threadIdx.x!=0 || blockIdx.x!=0) return;
  float M = 0.f;
  if(rowstart[N] != Et) M = 400.f;
  else {
    int allz = 1;
    for(int i=0;i<128;i++) if(h[i]!=0.f){ allz=0; break; }
    if(allz) M = 500.f;
  }
  if(M != 0.f) out[0] = M;
}

// ---- zero counts[N] and relmean[16] ----
__global__ void k_zero(int* __restrict__ counts, float* __restrict__ relmean, int N){
  int i = blockIdx.x*blockDim.x + threadIdx.x;
  if(i < N) counts[i] = 0;
  if(i < 16) relmean[i] = 0.f;
}

// ---- relation mean over E rows of 16 (f32) ----
__global__ void k_relmean(const float* __restrict__ rel, float* __restrict__ relmean, int E){
  __shared__ float red[256][16];
  float s[16];
#pragma unroll
  for(int j=0;j<16;j++) s[j]=0.f;
  for(int r = blockIdx.x*blockDim.x + threadIdx.x; r < E; r += gridDim.x*blockDim.x){
    const float4* p = (const float4*)(rel + (size_t)r*16);
    float4 a=p[0], b=p[1], c=p[2], d=p[3];
    s[0]+=a.x; s[1]+=a.y; s[2]+=a.z; s[3]+=a.w;
    s[4]+=b.x; s[5]+=b.y; s[6]+=b.z; s[7]+=b.w;
    s[8]+=c.x; s[9]+=c.y; s[10]+=c.z; s[11]+=c.w;
    s[12]+=d.x; s[13]+=d.y; s[14]+=d.z; s[15]+=d.w;
  }
  int tid = threadIdx.x;
#pragma unroll
  for(int j=0;j<16;j++) red[tid][j]=s[j];
  __syncthreads();
  for(int off=128; off>0; off>>=1){
    if(tid<off){
#pragma unroll
      for(int j=0;j<16;j++) red[tid][j]+=red[tid+off][j];
    }
    __syncthreads();
  }
  if(tid<16) atomicAdd(relmean+tid, red[0][tid]*(1.0f/(float)E));
}

// ---- CSR build ----
__global__ void k_count(const int* __restrict__ edges, int* __restrict__ counts, int E, int N){
  int Et = E + N;
  int e = blockIdx.x*blockDim.x + threadIdx.x;
  if(e>=Et) return;
  int d = (e<E) ? edges[E+e] : (e-E);
  if(d<0) d=0; if(d>=N) d=N-1;
  atomicAdd(counts+d, 1);
}

__global__ void k_scan(const int* __restrict__ counts, int* __restrict__ rowstart,
                       int* __restrict__ cursor, int N){
  __shared__ int part[1024];
  int tid = threadIdx.x;
  int chunk = (N + 1023) >> 10;
  int lo = tid*chunk, hi = lo+chunk; if(hi>N) hi=N; if(lo>N) lo=N;
  int s=0;
  for(int i=lo;i<hi;i++) s += counts[i];
  part[tid]=s;
  __syncthreads();
  for(int off=1; off<1024; off<<=1){
    int v = (tid>=off) ? part[tid-off] : 0;
    __syncthreads();
    part[tid] += v;
    __syncthreads();
  }
  int run = (tid==0) ? 0 : part[tid-1];
  for(int i=lo;i<hi;i++){ rowstart[i]=run; cursor[i]=run; run += counts[i]; }
  if(tid==1023) rowstart[N] = part[1023];
}

__global__ void k_scatter(const int* __restrict__ edges, int* __restrict__ cursor,
                          int* __restrict__ adj_src, int* __restrict__ adj_eid, int E, int N){
  int Et = E + N;
  int e = blockIdx.x*blockDim.x + threadIdx.x;
  if(e>=Et) return;
  int s, d;
  if(e<E){ s=edges[e]; d=edges[E+e]; } else { s=e-E; d=s; }
  if(d<0) d=0; if(d>=N) d=N-1;
  int pos = atomicAdd(cursor+d, 1);
  adj_src[pos]=s; adj_eid[pos]=e;
}

// ---- embedding + input projection: h[N][64] (f32) ----
__global__ void k_embed(const float* __restrict__ nodes,
                        const float* __restrict__ time_emb, const float* __restrict__ type_emb,
                        const float* __restrict__ biway_emb, const float* __restrict__ islink_emb,
                        const float* __restrict__ projw, const float* __restrict__ projb,
                        float* __restrict__ h, int N){
  __shared__ float W[64][65];
  __shared__ float h0[4][64];
  int tid = threadIdx.x;
  for(int i=tid; i<64*64; i+=256) W[i>>6][i&63] = projw[i];
  __syncthreads();
  int wave = tid>>6, lane = tid&63;
  int node = blockIdx.x*4 + wave;
  if(node<N){
    const float* nr = nodes + (size_t)node*20;
    float v; int c = lane;
    if(c<16){
      int t=(int)nr[0]; t = t<0?0:(t>287?287:t);
      v = time_emb[t*16+c];
    } else if(c<32){
      int ty=(int)nr[1]; ty = ty<0?0:(ty>15?15:ty);
      v = type_emb[ty*16+(c-16)];
    } else if(c<40){
      int bw=(int)nr[2]; bw = bw<0?0:(bw>1?1:bw);
      v = biway_emb[bw*8+(c-32)];
    } else if(c<48){
      int il=(int)nr[3]; il = il<0?0:(il>1?1:il);
      v = islink_emb[il*8+(c-40)];
    } else {
      v = nr[4 + (c-48)];
    }
    h0[wave][lane]=v;
  }
  __syncthreads();
  if(node<N){
    float acc = projb[lane];
#pragma unroll
    for(int k=0;k<64;k++) acc += W[lane][k]*h0[wave][k];
    h[(size_t)node*64+lane]=acc;
  }
}

// ---- xl/xr = h @ {wl,wr}.T + {bl,br}, stored bf16. 16 nodes/block ----
__global__ void k_xlr(const float* __restrict__ h,
                      const float* __restrict__ wl, const float* __restrict__ bl,
                      const float* __restrict__ wr, const float* __restrict__ br,
                      u16* __restrict__ xl, u16* __restrict__ xr, int N){
  __shared__ float hs[NT*64];
  int tid = threadIdx.x;
  int base = blockIdx.x*NT;
  int nvalid = N - base; if(nvalid > NT) nvalid = NT;
  if(nvalid == NT){
    *(float4*)(hs + tid*4) = *(const float4*)(h + (size_t)base*64 + tid*4);
  } else {
    for(int i=tid; i<NT*64; i+=256) hs[i] = (i < nvalid*64) ? h[(size_t)base*64+i] : 0.f;
  }
  __syncthreads();
  int o = tid;   // output channel 0..255
  const float4* wl4 = (const float4*)(wl + (size_t)o*64);
  const float4* wr4 = (const float4*)(wr + (size_t)o*64);
  float blv = bl[o], brv = br[o];
  float accl[NT], accr[NT];
#pragma unroll
  for(int n=0;n<NT;n++){ accl[n]=blv; accr[n]=brv; }
  for(int kk=0; kk<16; kk++){
    float4 a = wl4[kk];
    float4 b = wr4[kk];
#pragma unroll
    for(int n=0;n<NT;n++){
      float4 hv = *(const float4*)(hs + n*64 + kk*4);
      accl[n] += a.x*hv.x + a.y*hv.y + a.z*hv.z + a.w*hv.w;
      accr[n] += b.x*hv.x + b.y*hv.y + b.z*hv.z + b.w*hv.w;
    }
  }
  for(int n=0;n<nvalid;n++){
    xl[(size_t)(base+n)*HHID + o] = f2bf(accl[n]);
    xr[(size_t)(base+n)*HHID + o] = f2bf(accr[n]);
  }
}

// ---- fused per-node: edge logits + online softmax + aggregation + residual ----
// we/att/gat_b pre-offset for the layer. One wave per node (grid-stride).
// Lane owns 4 consecutive channels (head = lane>>4).
__global__ void k_fused(const int* __restrict__ rowstart, const int* __restrict__ adj_src,
                        const int* __restrict__ adj_eid,
                        const float* __restrict__ relation, const float* __restrict__ relmean,
                        const float* __restrict__ we, const float* __restrict__ att,
                        const u16* __restrict__ xl, const u16* __restrict__ xr,
                        const float* __restrict__ gat_b,
                        float* __restrict__ h, int N, int E, float* __restrict__ outp){
  const int lane = threadIdx.x & 63;
  const int head = lane >> 4, sub = lane & 15;
  const int wid = (blockIdx.x*blockDim.x + threadIdx.x) >> 6;
  const int nw  = (gridDim.x*blockDim.x) >> 6;

  // per-wave constants: this lane's 4 we-rows (64 floats), att quad, relmean
  float wreg[64];
  {
    const float4* wp = (const float4*)(we + (size_t)lane*64);
#pragma unroll
    for(int i=0;i<16;i++){
      float4 t = wp[i];
      wreg[i*4+0]=t.x; wreg[i*4+1]=t.y; wreg[i*4+2]=t.z; wreg[i*4+3]=t.w;
    }
  }
  const float4 at4 = *(const float4*)(att + lane*4);

  for(int node = wid; node < N; node += nw){
    const int lo = rowstart[node], hi = rowstart[node+1];
    // xr row for this node: one 8B load per lane
    uint2 pb = *(const uint2*)(xr + (size_t)node*HHID + lane*4);
    float bv0=bflo(pb.x), bv1=bfhi(pb.x), bv2=bflo(pb.y), bv3=bfhi(pb.y);

    float m = -1e30f, den = 0.f;
    float a0=0.f, a1=0.f, a2=0.f, a3=0.f;

    // prefetch first neighbor's indices
    int eid0=0, sv0=0;
    if(lo < hi){ eid0 = adj_eid[lo]; sv0 = adj_src[lo]; }

    for(int p=lo; p<hi; p++){
      // prefetch next indices (breaks the idx->data chain)
      int eid1=0, sv1=0;
      if(p+1 < hi){ eid1 = adj_eid[p+1]; sv1 = adj_src[p+1]; }
      int sv = sv0; if(sv<0) sv=0; if(sv>=N) sv=N-1;

      // gather current data
      float rc[16];
      {
        const float4* rp = (eid0 < E) ? (const float4*)(relation + (size_t)eid0*16)
                                      : (const float4*)relmean;
        float4 q0=rp[0], q1=rp[1], q2=rp[2], q3=rp[3];
        rc[0]=q0.x; rc[1]=q0.y; rc[2]=q0.z; rc[3]=q0.w;
        rc[4]=q1.x; rc[5]=q1.y; rc[6]=q1.z; rc[7]=q1.w;
        rc[8]=q2.x; rc[9]=q2.y; rc[10]=q2.z; rc[11]=q2.w;
        rc[12]=q3.x; rc[13]=q3.y; rc[14]=q3.z; rc[15]=q3.w;
      }
      uint2 pa = *(const uint2*)(xl + (size_t)sv*HHID + lane*4);
      float av0=bflo(pa.x), av1=bfhi(pa.x), av2=bflo(pa.y), av3=bfhi(pa.y);

      // logit for this edge
      float c = 0.f;
#pragma unroll
      for(int j=0;j<4;j++){
        float ep = 0.f;
#pragma unroll
        for(int k=0;k<16;k++) ep += rc[k]*wreg[j*16+k];
        float avj = (j==0)?av0:(j==1)?av1:(j==2)?av2:av3;
        float bvj = (j==0)?bv0:(j==1)?bv1:(j==2)?bv2:bv3;
        float mm = avj + bvj + ep;
        mm = (mm>0.f) ? mm : 0.2f*mm;
        float atj = (j==0)?at4.x:(j==1)?at4.y:(j==2)?at4.z:at4.w;
        c += mm*atj;
      }
      c += __shfl_xor(c, 1);
      c += __shfl_xor(c, 2);
      c += __shfl_xor(c, 4);
      c += __shfl_xor(c, 8);

      // online softmax update (uniform within the 16-lane head group)
      if(c > m){
        float sc = __expf(m - c);
        den *= sc; a0 *= sc; a1 *= sc; a2 *= sc; a3 *= sc;
        m = c;
      }
      float wgt = __expf(c - m);
      den += wgt;
      a0 += wgt*av0; a1 += wgt*av1; a2 += wgt*av2; a3 += wgt*av3;

      eid0 = eid1; sv0 = sv1;
    }

    float inv = 1.0f/den;   // den>0: every node has a self-loop
    float v0=a0*inv, v1=a1*inv, v2=a2*inv, v3=a3*inv;
    v0 += __shfl_xor(v0,16); v0 += __shfl_xor(v0,32);
    v1 += __shfl_xor(v1,16); v1 += __shfl_xor(v1,32);
    v2 += __shfl_xor(v2,16); v2 += __shfl_xor(v2,32);
    v3 += __shfl_xor(v3,16); v3 += __shfl_xor(v3,32);
    if(lane < 16){
      int cb = sub*4;
      float4 hv = *(const float4*)(h + (size_t)node*64 + cb);
      const float4 gb = *(const float4*)(gat_b + cb);
      float o0 = fmaxf(0.25f*v0 + gb.x + hv.x, 0.f);
      float o1 = fmaxf(0.25f*v1 + gb.y + hv.y, 0.f);
      float o2 = fmaxf(0.25f*v2 + gb.z + hv.z, 0.f);
      float o3 = fmaxf(0.25f*v3 + gb.w + hv.w, 0.f);
      *(float4*)(h + (size_t)node*64 + cb) = make_float4(o0,o1,o2,o3);
      if(outp) *(float4*)(outp + (size_t)node*64 + cb) = make_float4(o0,o1,o2,o3);
    }
  }
}

extern "C" void kernel_launch(void* const* d_in, const int* in_sizes, int n_in,
                              void* d_out, int out_size, void* d_ws, size_t ws_size,
                              hipStream_t stream) {
  const float* nodes     = (const float*)d_in[0];
  const int*   edges     = (const int*)d_in[1];
  const float* relation  = (const float*)d_in[2];
  const float* time_emb  = (const float*)d_in[3];
  const float* type_emb  = (const float*)d_in[4];
  const float* biway_emb = (const float*)d_in[5];
  const float* islink_emb= (const float*)d_in[6];
  const float* proj_w    = (const float*)d_in[7];
  const float* proj_b    = (const float*)d_in[8];
  const float* lin_l_w   = (const float*)d_in[9];
  const float* lin_l_b   = (const float*)d_in[10];
  const float* lin_r_w   = (const float*)d_in[11];
  const float* lin_r_b   = (const float*)d_in[12];
  const float* lin_e_w   = (const float*)d_in[13];
  const float* att       = (const float*)d_in[14];
  const float* gat_b     = (const float*)d_in[15];

  const int N  = in_sizes[0] / 20;
  const int E  = in_sizes[1] / 2;
  const int Et = E + N;

  size_t off = 0;
  auto alloc = [&](size_t bytes)->size_t {
    size_t p = off;
    off += ((bytes + 255) / 256) * 256;
    return p;
  };
  size_t o_h        = alloc((size_t)N*64*4);        // f32
  size_t o_xl       = alloc((size_t)N*HHID*2);      // bf16
  size_t o_xr       = alloc((size_t)N*HHID*2);      // bf16
  size_t o_relmean  = alloc(64*4);
  size_t o_counts   = alloc((size_t)N*4);
  size_t o_rowstart = alloc((size_t)(N+1)*4);
  size_t o_cursor   = alloc((size_t)(N+1)*4);
  size_t o_adjsrc   = alloc((size_t)Et*4);
  size_t o_adjeid   = alloc((size_t)Et*4);

  if (off > ws_size) {
    TopoAggregator_33217277067466_kernel<<<2048, 256, 0, stream>>>(
        (float*)d_out, out_size, 100.0f);   // marker ~100: ws too small
    return;
  }

  char* w = (char*)d_ws;
  float* h        = (float*)(w + o_h);
  u16*   xl       = (u16*)(w + o_xl);
  u16*   xr       = (u16*)(w + o_xr);
  float* relmean  = (float*)(w + o_relmean);
  int*   counts   = (int*)(w + o_counts);
  int*   rowstart = (int*)(w + o_rowstart);
  int*   cursor   = (int*)(w + o_cursor);
  int*   adj_src  = (int*)(w + o_adjsrc);
  int*   adj_eid  = (int*)(w + o_adjeid);

  k_zero<<<(N+255)/256, 256, 0, stream>>>(counts, relmean, N);
  k_relmean<<<64, 256, 0, stream>>>(relation, relmean, E);
  k_count<<<(Et+255)/256, 256, 0, stream>>>(edges, counts, E, N);
  k_scan<<<1, 1024, 0, stream>>>(counts, rowstart, cursor, N);
  k_scatter<<<(Et+255)/256, 256, 0, stream>>>(edges, cursor, adj_src, adj_eid, E, N);

  k_embed<<<(N+3)/4, 256, 0, stream>>>(nodes, time_emb, type_emb, biway_emb, islink_emb,
                                       proj_w, proj_b, h, N);

  for(int l=0; l<2; l++){
    k_xlr<<<(N+NT-1)/NT, 256, 0, stream>>>(h,
        lin_l_w + (size_t)l*HHID*64, lin_l_b + (size_t)l*HHID,
        lin_r_w + (size_t)l*HHID*64, lin_r_b + (size_t)l*HHID,
        xl, xr, N);
    k_fused<<<4096, 256, 0, stream>>>(rowstart, adj_src, adj_eid,
        relation, relmean,
        lin_e_w + (size_t)l*HHID*16, att + (size_t)l*HEADS*64,
        xl, xr, gat_b + (size_t)l*64,
        h, N, E,
        (l==1) ? (float*)d_out : (float*)nullptr);
  }
  k_marker<<<1, 64, 0, stream>>>(rowstart, h, (float*)d_out, N, Et);
}